// Round 1
// baseline (1466.339 us; speedup 1.0000x reference)
//
#include <hip/hip_runtime.h>
#include <math.h>

#define NB 4
#define NP 4096
#define KNB 20
#define VEPS 1e-6f
#define BNEPS 1e-5f

// ---------------- zero out + stats ----------------
__global__ void zero_kernel(float* a, int na, float* b, int nb) {
  int i = blockIdx.x * 256 + threadIdx.x;
  if (i < na) a[i] = 0.f;
  if (i < nb) b[i] = 0.f;
}

// ---------------- KNN: one wave per query ----------------
__global__ __launch_bounds__(256) void knn_kernel(const float* __restrict__ x,
                                                  int* __restrict__ idxout) {
  __shared__ float sx[NP], sy[NP], sz[NP];
  const int b = blockIdx.x >> 8;     // 256 blocks per batch
  const int blk = blockIdx.x & 255;
  const float* xb = x + b * NP * 3;
  for (int e = threadIdx.x; e < NP * 3; e += 256) {
    float v = xb[e];
    int p = e / 3;
    int c = e - p * 3;
    if (c == 0) sx[p] = v; else if (c == 1) sy[p] = v; else sz[p] = v;
  }
  __syncthreads();
  const int wave = threadIdx.x >> 6, lane = threadIdx.x & 63;
#pragma unroll 1
  for (int q = 0; q < 4; ++q) {
    const int n = blk * 16 + wave * 4 + q;
    const float qx = sx[n], qy = sy[n], qz = sz[n];
    const float sqq = qx * qx + qy * qy + qz * qz;
    float dv[64];
#pragma unroll
    for (int t = 0; t < 64; ++t) {
      int j = t * 64 + lane;
      float px = sx[j], py = sy[j], pz = sz[j];
      float inner = qx * px + qy * py + qz * pz;
      float sqj = px * px + py * py + pz * pz;
      dv[t] = 2.0f * inner - sqq - sqj;   // = -||xi-xj||^2, matches reference formula
    }
    unsigned long long alive = ~0ull;
    int* outp = idxout + (b * NP + n) * KNB;
#pragma unroll 1
    for (int r = 0; r < KNB; ++r) {
      float bv = -3.4e38f;
      int bt = 0;
#pragma unroll
      for (int t = 0; t < 64; ++t) {
        float v = ((alive >> t) & 1ull) ? dv[t] : -3.4e38f;
        if (v > bv) { bv = v; bt = t; }   // first max -> smallest t -> smallest j
      }
      unsigned ou = __float_as_uint(bv);
      ou = (ou & 0x80000000u) ? ~ou : (ou | 0x80000000u);   // order-preserving
      unsigned j = (unsigned)(bt * 64 + lane);
      unsigned long long key =
          ((unsigned long long)ou << 32) | (unsigned long long)(0xFFFFFFFFu - j);
#pragma unroll
      for (int s = 32; s; s >>= 1) {
        unsigned long long o = __shfl_xor(key, s, 64);
        if (o > key) key = o;
      }
      unsigned jw = 0xFFFFFFFFu - (unsigned)(key & 0xFFFFFFFFull);
      if (lane == 0) outp[r] = (int)jw;
      if ((int)(jw & 63u) == lane) alive &= ~(1ull << (jw >> 6));
    }
  }
}

// ---------------- BN1 stats: recompute edge features, lane = channel ----------------
__global__ __launch_bounds__(256) void bn1_stats_kernel(const float* __restrict__ x,
                                                        const int* __restrict__ idx,
                                                        const float* __restrict__ W1,
                                                        float* __restrict__ stats) {
  const int lane = threadIdx.x & 63, wave = threadIdx.x >> 6;
  const int gw = blockIdx.x * 4 + wave;        // 1024 waves total
  const float w0 = W1[lane * 3 + 0], w1 = W1[lane * 3 + 1], w2 = W1[lane * 3 + 2];
  float s = 0.f, ss = 0.f;
  const int NI = NB * NP * KNB;
  for (int item = gw; item < NI; item += 1024) {
    int b = item / (NP * KNB);
    int r = item - b * (NP * KNB);
    int n = r / KNB;
    int j = idx[item];
    const float* cp = x + (b * NP + n) * 3;
    const float* pp = x + (b * NP + j) * 3;
    float cx = cp[0], cy = cp[1], cz = cp[2];
    float nx = pp[0], ny = pp[1], nz = pp[2];
    float ux = nx - cx, uy = ny - cy, uz = nz - cz;
    float wx = ny * cz - nz * cy, wy = nz * cx - nx * cz, wz = nx * cy - ny * cx;
    float px = w0 * ux + w1 * cx + w2 * wx;
    float py = w0 * uy + w1 * cy + w2 * wy;
    float pz = w0 * uz + w1 * cz + w2 * wz;
    float nm = sqrtf(px * px + py * py + pz * pz) + VEPS;
    s += nm; ss += nm * nm;
  }
  __shared__ float red[2][4][64];
  red[0][wave][lane] = s; red[1][wave][lane] = ss;
  __syncthreads();
  if (wave == 0) {
    float a = red[0][0][lane] + red[0][1][lane] + red[0][2][lane] + red[0][3][lane];
    float c = red[1][0][lane] + red[1][1][lane] + red[1][2][lane] + red[1][3][lane];
    atomicAdd(&stats[lane], a);
    atomicAdd(&stats[64 + lane], c);
  }
}

// ---------------- BN finalize: sums -> (scale, mean) ----------------
__global__ void bn_finalize_kernel(float* stage, const float* __restrict__ gamma,
                                   int C, float invcnt) {
  int c = blockIdx.x * 256 + threadIdx.x;
  if (c >= C) return;
  float mean = stage[c] * invcnt;
  float var = stage[C + c] * invcnt - mean * mean;
  var = fmaxf(var, 0.f);
  stage[2 * C + c] = gamma[c] / sqrtf(var + BNEPS);
  stage[3 * C + c] = mean;
}

// ---------------- block1 apply + mean over K ----------------
__global__ __launch_bounds__(256) void block1_apply_kernel(
    const float* __restrict__ x, const int* __restrict__ idx,
    const float* __restrict__ W1, const float* __restrict__ D1,
    const float* __restrict__ stats, const float* __restrict__ beta,
    float* __restrict__ hout) {
  const int lane = threadIdx.x & 63, wave = threadIdx.x >> 6;
  const int b = blockIdx.x >> 8;
  const int nbase = (blockIdx.x & 255) * 16;
  const float w0 = W1[lane * 3], w1 = W1[lane * 3 + 1], w2 = W1[lane * 3 + 2];
  const float e0 = D1[lane * 3], e1 = D1[lane * 3 + 1], e2 = D1[lane * 3 + 2];
  const float sc = stats[128 + lane], mn = stats[192 + lane], be = beta[lane];
  __shared__ float lds[64 * 3 * 17];
#pragma unroll 1
  for (int q = 0; q < 4; ++q) {
    int nl = wave * 4 + q;
    int n = nbase + nl;
    const float* cp = x + (b * NP + n) * 3;
    float cx = cp[0], cy = cp[1], cz = cp[2];
    const int* ip = idx + (b * NP + n) * KNB;
    float ax = 0.f, ay = 0.f, az = 0.f;
    for (int k = 0; k < KNB; ++k) {
      int j = ip[k];
      const float* pp = x + (b * NP + j) * 3;
      float nx = pp[0], ny = pp[1], nz = pp[2];
      float ux = nx - cx, uy = ny - cy, uz = nz - cz;
      float wx = ny * cz - nz * cy, wy = nz * cx - nx * cz, wz = nx * cy - ny * cx;
      float px = w0 * ux + w1 * cx + w2 * wx;
      float py = w0 * uy + w1 * cy + w2 * wy;
      float pz = w0 * uz + w1 * cz + w2 * wz;
      float dx = e0 * ux + e1 * cx + e2 * wx;
      float dy = e0 * uy + e1 * cy + e2 * wy;
      float dz = e0 * uz + e1 * cz + e2 * wz;
      float nm = sqrtf(px * px + py * py + pz * pz) + VEPS;
      float fac = (sc * (nm - mn) + be) / nm;
      px *= fac; py *= fac; pz *= fac;
      float dot = px * dx + py * dy + pz * dz;
      if (dot < 0.f) {
        float tt = dot / (dx * dx + dy * dy + dz * dz + VEPS);
        px -= tt * dx; py -= tt * dy; pz -= tt * dz;
      }
      ax += px; ay += py; az += pz;
    }
    const float k1 = 1.f / (float)KNB;
    lds[(lane * 3 + 0) * 17 + nl] = ax * k1;
    lds[(lane * 3 + 1) * 17 + nl] = ay * k1;
    lds[(lane * 3 + 2) * 17 + nl] = az * k1;
  }
  __syncthreads();
  float* ob = hout + (size_t)(b * 64 * 3) * NP + nbase;
  for (int i = 0; i < 12; ++i) {
    int flat = i * 256 + threadIdx.x;   // 0..3071
    int ni = flat & 15, cv = flat >> 4; // cv = c*3+v, 0..191
    ob[(size_t)cv * NP + ni] = lds[cv * 17 + ni];
  }
}

// ---------------- unified VN GEMM block kernel ----------------
// PHASE 0: p = W@h, per-channel (sum, sumsq) of norms -> stage atomics
// PHASE 1: p = W@h, d = D@h, BN(p) + VN-leaky -> out (h_next)
// PHASE 2: p = W@h, BN(p), mean over n -> atomicAdd out   (conv5 tail)
__device__ __forceinline__ void fma_step(const float* __restrict__ wls,
                                         const float* __restrict__ hs,
                                         int k, int co0, int nl0,
                                         float (&acc)[4][3][4]) {
  float4 wa = *(const float4*)&wls[k * 64 + (co0 ^ ((k & 15) << 2))];
  float4 h0 = *(const float4*)&hs[(k * 3 + 0) * 64 + nl0];
  float4 h1 = *(const float4*)&hs[(k * 3 + 1) * 64 + nl0];
  float4 h2 = *(const float4*)&hs[(k * 3 + 2) * 64 + nl0];
  const float* wv = (const float*)&wa;
  const float* a0 = (const float*)&h0;
  const float* a1 = (const float*)&h1;
  const float* a2 = (const float*)&h2;
#pragma unroll
  for (int ci = 0; ci < 4; ++ci) {
#pragma unroll
    for (int nj = 0; nj < 4; ++nj) {
      acc[ci][0][nj] = fmaf(wv[ci], a0[nj], acc[ci][0][nj]);
      acc[ci][1][nj] = fmaf(wv[ci], a1[nj], acc[ci][1][nj]);
      acc[ci][2][nj] = fmaf(wv[ci], a2[nj], acc[ci][2][nj]);
    }
  }
}

template <int CIN, int COUT, int PHASE>
__global__ __launch_bounds__(256) void vn_gemm_kernel(
    const float* __restrict__ h, const float* __restrict__ Wp,
    const float* __restrict__ Wd, float* __restrict__ stage,
    const float* __restrict__ beta, float* __restrict__ out) {
  __shared__ float hs[64 * 3 * 64];   // 48 KB: k x v x n
  __shared__ float wls[64 * 64];      // 16 KB: k x co (xor-swizzled)
  const int t = threadIdx.x;
  const int b = blockIdx.z;
  const int n0 = blockIdx.x * 64;
  const int cobase = blockIdx.y * 64;
  const int ng = t & 15;
  const int co0 = (t >> 4) * 4;
  const int nl0 = ng * 4;

  float accp[4][3][4] = {};
  float accd[4][3][4] = {};

  for (int chunk = 0; chunk < CIN / 64; ++chunk) {
    const int kb = chunk * 64;
    const float* hbase = h + ((size_t)(b * CIN + kb) * 3) * NP + n0;
    __syncthreads();
#pragma unroll
    for (int i = 0; i < 12; ++i) {     // 192 rows x 64 floats
      int flat = i * 256 + t;
      int row = flat >> 4;
      int c4 = (flat & 15) * 4;
      *(float4*)&hs[row * 64 + c4] = *(const float4*)&hbase[(size_t)row * NP + c4];
    }
    {
      const float* Ws = (PHASE == 1) ? Wd : Wp;
#pragma unroll
      for (int i = 0; i < 16; ++i) {
        int flat = i * 256 + t;
        int co = flat >> 6, k = flat & 63;
        wls[k * 64 + (co ^ ((k & 15) << 2))] = Ws[(cobase + co) * CIN + kb + k];
      }
    }
    __syncthreads();
    if (PHASE == 1) {
#pragma unroll 2
      for (int k = 0; k < 64; ++k) fma_step(wls, hs, k, co0, nl0, accd);
      __syncthreads();
#pragma unroll
      for (int i = 0; i < 16; ++i) {
        int flat = i * 256 + t;
        int co = flat >> 6, k = flat & 63;
        wls[k * 64 + (co ^ ((k & 15) << 2))] = Wp[(cobase + co) * CIN + kb + k];
      }
      __syncthreads();
    }
#pragma unroll 2
    for (int k = 0; k < 64; ++k) fma_step(wls, hs, k, co0, nl0, accp);
  }

  if (PHASE == 0) {
#pragma unroll
    for (int ci = 0; ci < 4; ++ci) {
      float s = 0.f, ss = 0.f;
#pragma unroll
      for (int nj = 0; nj < 4; ++nj) {
        float nsq = accp[ci][0][nj] * accp[ci][0][nj] +
                    accp[ci][1][nj] * accp[ci][1][nj] +
                    accp[ci][2][nj] * accp[ci][2][nj];
        float nm = sqrtf(nsq) + VEPS;
        s += nm; ss += nm * nm;
      }
#pragma unroll
      for (int m = 1; m < 16; m <<= 1) {
        s += __shfl_xor(s, m, 64);
        ss += __shfl_xor(ss, m, 64);
      }
      if (ng == 0) {
        atomicAdd(&stage[cobase + co0 + ci], s);
        atomicAdd(&stage[COUT + cobase + co0 + ci], ss);
      }
    }
  } else if (PHASE == 1) {
#pragma unroll
    for (int ci = 0; ci < 4; ++ci) {
      const int ch = cobase + co0 + ci;
      const float sc = stage[2 * COUT + ch], mn = stage[3 * COUT + ch], be = beta[ch];
#pragma unroll
      for (int nj = 0; nj < 4; ++nj) {
        float px = accp[ci][0][nj], py = accp[ci][1][nj], pz = accp[ci][2][nj];
        float nm = sqrtf(px * px + py * py + pz * pz) + VEPS;
        float fac = (sc * (nm - mn) + be) / nm;
        px *= fac; py *= fac; pz *= fac;
        float dx = accd[ci][0][nj], dy = accd[ci][1][nj], dz = accd[ci][2][nj];
        float dot = px * dx + py * dy + pz * dz;
        if (dot < 0.f) {
          float tt = dot / (dx * dx + dy * dy + dz * dz + VEPS);
          px -= tt * dx; py -= tt * dy; pz -= tt * dz;
        }
        accp[ci][0][nj] = px; accp[ci][1][nj] = py; accp[ci][2][nj] = pz;
      }
#pragma unroll
      for (int v = 0; v < 3; ++v) {
        float4 o;
        o.x = accp[ci][v][0]; o.y = accp[ci][v][1];
        o.z = accp[ci][v][2]; o.w = accp[ci][v][3];
        *(float4*)&out[((size_t)(b * COUT + ch) * 3 + v) * NP + n0 + nl0] = o;
      }
    }
  } else {  // PHASE == 2
    const float invN = 1.f / (float)NP;
#pragma unroll
    for (int ci = 0; ci < 4; ++ci) {
      const int ch = cobase + co0 + ci;
      const float sc = stage[2 * COUT + ch], mn = stage[3 * COUT + ch], be = beta[ch];
      float p0 = 0.f, p1 = 0.f, p2 = 0.f;
#pragma unroll
      for (int nj = 0; nj < 4; ++nj) {
        float px = accp[ci][0][nj], py = accp[ci][1][nj], pz = accp[ci][2][nj];
        float nm = sqrtf(px * px + py * py + pz * pz) + VEPS;
        float fac = (sc * (nm - mn) + be) / nm;
        p0 += px * fac; p1 += py * fac; p2 += pz * fac;
      }
#pragma unroll
      for (int m = 1; m < 16; m <<= 1) {
        p0 += __shfl_xor(p0, m, 64);
        p1 += __shfl_xor(p1, m, 64);
        p2 += __shfl_xor(p2, m, 64);
      }
      if (ng == 0) {
        atomicAdd(&out[(size_t)(b * COUT + ch) * 3 + 0], p0 * invN);
        atomicAdd(&out[(size_t)(b * COUT + ch) * 3 + 1], p1 * invN);
        atomicAdd(&out[(size_t)(b * COUT + ch) * 3 + 2], p2 * invN);
      }
    }
  }
}

extern "C" void kernel_launch(void* const* d_in, const int* in_sizes, int n_in,
                              void* d_out, int out_size, void* d_ws, size_t ws_size,
                              hipStream_t stream) {
  const float* x  = (const float*)d_in[0];
  const float* W1 = (const float*)d_in[1];
  const float* D1 = (const float*)d_in[2];
  const float* g1 = (const float*)d_in[3];
  const float* b1 = (const float*)d_in[4];
  const float* W2 = (const float*)d_in[5];
  const float* D2 = (const float*)d_in[6];
  const float* g2 = (const float*)d_in[7];
  const float* b2 = (const float*)d_in[8];
  const float* W3 = (const float*)d_in[9];
  const float* D3 = (const float*)d_in[10];
  const float* g3 = (const float*)d_in[11];
  const float* b3 = (const float*)d_in[12];
  const float* W4 = (const float*)d_in[13];
  const float* D4 = (const float*)d_in[14];
  const float* g4 = (const float*)d_in[15];
  const float* b4 = (const float*)d_in[16];
  const float* W5 = (const float*)d_in[17];
  const float* g5 = (const float*)d_in[18];
  const float* b5 = (const float*)d_in[19];
  float* outp = (float*)d_out;

  char* ws = (char*)d_ws;
  size_t off = 0;
  int* idxw = (int*)(ws + off); off += 4ull * NB * NP * KNB;     // 1.31 MB
  off = (off + 255) & ~255ull;
  float* stats = (float*)(ws + off); off += 4ull * 20480;        // 80 KB (5 stages x 4096)
  off = (off + 255) & ~255ull;
  float* hA = (float*)(ws + off); off += 4ull * NB * 64 * 3 * NP;   // 12.6 MB
  off = (off + 255) & ~255ull;
  float* hB = (float*)(ws + off); off += 4ull * NB * 128 * 3 * NP;  // 25.2 MB

  float* st1 = stats;
  float* st2 = stats + 4096;
  float* st3 = stats + 8192;
  float* st4 = stats + 12288;
  float* st5 = stats + 16384;

  zero_kernel<<<80, 256, 0, stream>>>(outp, out_size, stats, 20480);
  knn_kernel<<<NB * 256, 256, 0, stream>>>(x, idxw);

  bn1_stats_kernel<<<256, 256, 0, stream>>>(x, idxw, W1, st1);
  bn_finalize_kernel<<<1, 64, 0, stream>>>(st1, g1, 64, 1.f / (float)(NB * NP * KNB));
  block1_apply_kernel<<<NB * 256, 256, 0, stream>>>(x, idxw, W1, D1, st1, b1, hA);

  vn_gemm_kernel<64, 64, 0><<<dim3(64, 1, NB), 256, 0, stream>>>(hA, W2, nullptr, st2, nullptr, nullptr);
  bn_finalize_kernel<<<1, 64, 0, stream>>>(st2, g2, 64, 1.f / (float)(NB * NP));
  vn_gemm_kernel<64, 64, 1><<<dim3(64, 1, NB), 256, 0, stream>>>(hA, W2, D2, st2, b2, hB);

  vn_gemm_kernel<64, 64, 0><<<dim3(64, 1, NB), 256, 0, stream>>>(hB, W3, nullptr, st3, nullptr, nullptr);
  bn_finalize_kernel<<<1, 64, 0, stream>>>(st3, g3, 64, 1.f / (float)(NB * NP));
  vn_gemm_kernel<64, 64, 1><<<dim3(64, 1, NB), 256, 0, stream>>>(hB, W3, D3, st3, b3, hA);

  vn_gemm_kernel<64, 128, 0><<<dim3(64, 2, NB), 256, 0, stream>>>(hA, W4, nullptr, st4, nullptr, nullptr);
  bn_finalize_kernel<<<1, 128, 0, stream>>>(st4, g4, 128, 1.f / (float)(NB * NP));
  vn_gemm_kernel<64, 128, 1><<<dim3(64, 2, NB), 256, 0, stream>>>(hA, W4, D4, st4, b4, hB);

  vn_gemm_kernel<128, 1024, 0><<<dim3(64, 16, NB), 256, 0, stream>>>(hB, W5, nullptr, st5, nullptr, nullptr);
  bn_finalize_kernel<<<4, 256, 0, stream>>>(st5, g5, 1024, 1.f / (float)(NB * NP));
  vn_gemm_kernel<128, 1024, 2><<<dim3(64, 16, NB), 256, 0, stream>>>(hB, W5, nullptr, st5, b5, outp);
}

// Round 4
// 1268.303 us; speedup vs baseline: 1.1561x; 1.1561x over previous
//
#include <hip/hip_runtime.h>
#include <math.h>

#define NB 4
#define NP 4096
#define KNB 20
#define VEPS 1e-6f
#define BNEPS 1e-5f

// ---------------- zero out + stats ----------------
__global__ void zero_kernel(float* a, int na, float* b, int nb) {
  int i = blockIdx.x * 256 + threadIdx.x;
  if (i < na) a[i] = 0.f;
  if (i < nb) b[i] = 0.f;
}

// ---------------- KNN: one wave per query, threshold-extraction ----------------
// 512 threads (8 waves) per block, 4 queries per wave -> 32 queries/block.
// grid = NB*128 = 512 blocks -> all resident (2/CU), no tail.
__global__ __launch_bounds__(512) void knn_kernel(const float* __restrict__ x,
                                                  int* __restrict__ idxout) {
  __shared__ float sx[NP], sy[NP], sz[NP];
  const int b = blockIdx.x >> 7;
  const int blk = blockIdx.x & 127;
  const float* xb = x + b * NP * 3;
  for (int e = threadIdx.x; e < NP * 3; e += 512) {
    float v = xb[e];
    int p = e / 3;
    int c = e - p * 3;
    if (c == 0) sx[p] = v; else if (c == 1) sy[p] = v; else sz[p] = v;
  }
  __syncthreads();
  const int wave = threadIdx.x >> 6, lane = threadIdx.x & 63;
  const float NEGINF = -__builtin_inff();
#pragma unroll 1
  for (int q = 0; q < 4; ++q) {
    const int n = blk * 32 + wave * 4 + q;
    const float qx = sx[n], qy = sy[n], qz = sz[n];
    const float sqq = qx * qx + qy * qy + qz * qz;
    float dv[64];
#pragma unroll
    for (int t = 0; t < 64; ++t) {
      int j = t * 64 + lane;
      float px = sx[j], py = sy[j], pz = sz[j];
      float inner = qx * px + qy * py + qz * pz;
      float sqj = px * px + py * py + pz * pz;
      dv[t] = 2.0f * inner - sqq - sqj;   // = -||xi-xj||^2, reference order
    }
    float thr = __builtin_inff();
    unsigned sel = 0u;
    int* outp = idxout + (b * NP + n) * KNB;
#pragma unroll 1
    for (int r = 0; r < KNB; ++r) {
      // ---- phase A: masked max of eligible values (tree, max3-friendly) ----
      float a0 = NEGINF, a1 = NEGINF, a2 = NEGINF, a3 = NEGINF;
      float a4 = NEGINF, a5 = NEGINF, a6 = NEGINF, a7 = NEGINF;
#pragma unroll
      for (int i = 0; i < 8; ++i) {
        float e0 = (dv[i * 8 + 0] < thr) ? dv[i * 8 + 0] : NEGINF;
        float e1 = (dv[i * 8 + 1] < thr) ? dv[i * 8 + 1] : NEGINF;
        float e2 = (dv[i * 8 + 2] < thr) ? dv[i * 8 + 2] : NEGINF;
        float e3 = (dv[i * 8 + 3] < thr) ? dv[i * 8 + 3] : NEGINF;
        float e4 = (dv[i * 8 + 4] < thr) ? dv[i * 8 + 4] : NEGINF;
        float e5 = (dv[i * 8 + 5] < thr) ? dv[i * 8 + 5] : NEGINF;
        float e6 = (dv[i * 8 + 6] < thr) ? dv[i * 8 + 6] : NEGINF;
        float e7 = (dv[i * 8 + 7] < thr) ? dv[i * 8 + 7] : NEGINF;
        float m012 = fmaxf(fmaxf(e0, e1), e2);   // v_max3
        float m345 = fmaxf(fmaxf(e3, e4), e5);
        float m67 = fmaxf(e6, e7);
        float mi = fmaxf(fmaxf(m012, m345), m67);
        switch (i) {  // static mapping to independent accumulators
          case 0: a0 = mi; break; case 1: a1 = mi; break;
          case 2: a2 = mi; break; case 3: a3 = mi; break;
          case 4: a4 = mi; break; case 5: a5 = mi; break;
          case 6: a6 = mi; break; case 7: a7 = mi; break;
        }
      }
      float m = fmaxf(fmaxf(fmaxf(a0, a1), fmaxf(a2, a3)),
                      fmaxf(fmaxf(a4, a5), fmaxf(a6, a7)));
#pragma unroll
      for (int s = 32; s; s >>= 1) m = fmaxf(m, __shfl_xor(m, s, 64));
      // ---- phase B: min index among candidates equal to m ----
      unsigned b0 = 0x7FFFFFFFu, b1 = 0x7FFFFFFFu, b2 = 0x7FFFFFFFu, b3 = 0x7FFFFFFFu;
#pragma unroll
      for (int i = 0; i < 4; ++i) {
        unsigned u[16];
#pragma unroll
        for (int k = 0; k < 16; ++k) {
          int t = i * 16 + k;
          unsigned jt = (unsigned)(t * 64) | (unsigned)lane;
          u[k] = (dv[t] == m) ? jt : 0x7FFFFFFFu;
        }
        unsigned c0 = min(min(u[0], u[1]), u[2]);    // v_min3
        unsigned c1 = min(min(u[3], u[4]), u[5]);
        unsigned c2 = min(min(u[6], u[7]), u[8]);
        unsigned c3 = min(min(u[9], u[10]), u[11]);
        unsigned c4 = min(min(u[12], u[13]), u[14]);
        unsigned mi = min(min(min(c0, c1), min(c2, c3)), min(c4, u[15]));
        switch (i) {
          case 0: b0 = mi; break; case 1: b1 = mi; break;
          case 2: b2 = mi; break; case 3: b3 = mi; break;
        }
      }
      unsigned jm = min(min(b0, b1), min(b2, b3));
#pragma unroll
      for (int s = 32; s; s >>= 1) jm = min(jm, (unsigned)__shfl_xor((int)jm, s, 64));
      thr = m;
      sel = ((int)lane == r) ? jm : sel;
    }
    if (lane < KNB) outp[lane] = (int)sel;
  }
}

// ---------------- BN1 stats: recompute edge features, lane = channel ----------------
__global__ __launch_bounds__(256) void bn1_stats_kernel(const float* __restrict__ x,
                                                        const int* __restrict__ idx,
                                                        const float* __restrict__ W1,
                                                        float* __restrict__ stats) {
  const int lane = threadIdx.x & 63, wave = threadIdx.x >> 6;
  const int gw = blockIdx.x * 4 + wave;        // 1024 waves total
  const float w0 = W1[lane * 3 + 0], w1 = W1[lane * 3 + 1], w2 = W1[lane * 3 + 2];
  float s = 0.f, ss = 0.f;
  const int NI = NB * NP * KNB;
  for (int item = gw; item < NI; item += 1024) {
    int b = item / (NP * KNB);
    int r = item - b * (NP * KNB);
    int n = r / KNB;
    int j = idx[item];
    const float* cp = x + (b * NP + n) * 3;
    const float* pp = x + (b * NP + j) * 3;
    float cx = cp[0], cy = cp[1], cz = cp[2];
    float nx = pp[0], ny = pp[1], nz = pp[2];
    float ux = nx - cx, uy = ny - cy, uz = nz - cz;
    float wx = ny * cz - nz * cy, wy = nz * cx - nx * cz, wz = nx * cy - ny * cx;
    float px = w0 * ux + w1 * cx + w2 * wx;
    float py = w0 * uy + w1 * cy + w2 * wy;
    float pz = w0 * uz + w1 * cz + w2 * wz;
    float nm = sqrtf(px * px + py * py + pz * pz) + VEPS;
    s += nm; ss += nm * nm;
  }
  __shared__ float red[2][4][64];
  red[0][wave][lane] = s; red[1][wave][lane] = ss;
  __syncthreads();
  if (wave == 0) {
    float a = red[0][0][lane] + red[0][1][lane] + red[0][2][lane] + red[0][3][lane];
    float c = red[1][0][lane] + red[1][1][lane] + red[1][2][lane] + red[1][3][lane];
    atomicAdd(&stats[lane], a);
    atomicAdd(&stats[64 + lane], c);
  }
}

// ---------------- BN finalize: sums -> (scale, mean) ----------------
__global__ void bn_finalize_kernel(float* stage, const float* __restrict__ gamma,
                                   int C, float invcnt) {
  int c = blockIdx.x * 256 + threadIdx.x;
  if (c >= C) return;
  float mean = stage[c] * invcnt;
  float var = stage[C + c] * invcnt - mean * mean;
  var = fmaxf(var, 0.f);
  stage[2 * C + c] = gamma[c] / sqrtf(var + BNEPS);
  stage[3 * C + c] = mean;
}

// ---------------- block1 apply + mean over K ----------------
__global__ __launch_bounds__(256) void block1_apply_kernel(
    const float* __restrict__ x, const int* __restrict__ idx,
    const float* __restrict__ W1, const float* __restrict__ D1,
    const float* __restrict__ stats, const float* __restrict__ beta,
    float* __restrict__ hout) {
  const int lane = threadIdx.x & 63, wave = threadIdx.x >> 6;
  const int b = blockIdx.x >> 8;
  const int nbase = (blockIdx.x & 255) * 16;
  const float w0 = W1[lane * 3], w1 = W1[lane * 3 + 1], w2 = W1[lane * 3 + 2];
  const float e0 = D1[lane * 3], e1 = D1[lane * 3 + 1], e2 = D1[lane * 3 + 2];
  const float sc = stats[128 + lane], mn = stats[192 + lane], be = beta[lane];
  __shared__ float lds[64 * 3 * 17];
#pragma unroll 1
  for (int q = 0; q < 4; ++q) {
    int nl = wave * 4 + q;
    int n = nbase + nl;
    const float* cp = x + (b * NP + n) * 3;
    float cx = cp[0], cy = cp[1], cz = cp[2];
    const int* ip = idx + (b * NP + n) * KNB;
    float ax = 0.f, ay = 0.f, az = 0.f;
    for (int k = 0; k < KNB; ++k) {
      int j = ip[k];
      const float* pp = x + (b * NP + j) * 3;
      float nx = pp[0], ny = pp[1], nz = pp[2];
      float ux = nx - cx, uy = ny - cy, uz = nz - cz;
      float wx = ny * cz - nz * cy, wy = nz * cx - nx * cz, wz = nx * cy - ny * cx;
      float px = w0 * ux + w1 * cx + w2 * wx;
      float py = w0 * uy + w1 * cy + w2 * wy;
      float pz = w0 * uz + w1 * cz + w2 * wz;
      float dx = e0 * ux + e1 * cx + e2 * wx;
      float dy = e0 * uy + e1 * cy + e2 * wy;
      float dz = e0 * uz + e1 * cz + e2 * wz;
      float nm = sqrtf(px * px + py * py + pz * pz) + VEPS;
      float fac = (sc * (nm - mn) + be) / nm;
      px *= fac; py *= fac; pz *= fac;
      float dot = px * dx + py * dy + pz * dz;
      if (dot < 0.f) {
        float tt = dot / (dx * dx + dy * dy + dz * dz + VEPS);
        px -= tt * dx; py -= tt * dy; pz -= tt * dz;
      }
      ax += px; ay += py; az += pz;
    }
    const float k1 = 1.f / (float)KNB;
    lds[(lane * 3 + 0) * 17 + nl] = ax * k1;
    lds[(lane * 3 + 1) * 17 + nl] = ay * k1;
    lds[(lane * 3 + 2) * 17 + nl] = az * k1;
  }
  __syncthreads();
  float* ob = hout + (size_t)(b * 64 * 3) * NP + nbase;
  for (int i = 0; i < 12; ++i) {
    int flat = i * 256 + threadIdx.x;   // 0..3071
    int ni = flat & 15, cv = flat >> 4; // cv = c*3+v, 0..191
    ob[(size_t)cv * NP + ni] = lds[cv * 17 + ni];
  }
}

// ---------------- unified VN GEMM block kernel ----------------
__device__ __forceinline__ void fma_step(const float* __restrict__ wls,
                                         const float* __restrict__ hs,
                                         int k, int co0, int nl0,
                                         float (&acc)[4][3][4]) {
  float4 wa = *(const float4*)&wls[k * 64 + (co0 ^ ((k & 15) << 2))];
  float4 h0 = *(const float4*)&hs[(k * 3 + 0) * 64 + nl0];
  float4 h1 = *(const float4*)&hs[(k * 3 + 1) * 64 + nl0];
  float4 h2 = *(const float4*)&hs[(k * 3 + 2) * 64 + nl0];
  const float* wv = (const float*)&wa;
  const float* a0 = (const float*)&h0;
  const float* a1 = (const float*)&h1;
  const float* a2 = (const float*)&h2;
#pragma unroll
  for (int ci = 0; ci < 4; ++ci) {
#pragma unroll
    for (int nj = 0; nj < 4; ++nj) {
      acc[ci][0][nj] = fmaf(wv[ci], a0[nj], acc[ci][0][nj]);
      acc[ci][1][nj] = fmaf(wv[ci], a1[nj], acc[ci][1][nj]);
      acc[ci][2][nj] = fmaf(wv[ci], a2[nj], acc[ci][2][nj]);
    }
  }
}

template <int CIN, int COUT, int PHASE>
__global__ __launch_bounds__(256) void vn_gemm_kernel(
    const float* __restrict__ h, const float* __restrict__ Wp,
    const float* __restrict__ Wd, float* __restrict__ stage,
    const float* __restrict__ beta, float* __restrict__ out) {
  __shared__ float hs[64 * 3 * 64];   // 48 KB: k x v x n
  __shared__ float wls[64 * 64];      // 16 KB: k x co (xor-swizzled)
  const int t = threadIdx.x;
  const int b = blockIdx.z;
  const int n0 = blockIdx.x * 64;
  const int cobase = blockIdx.y * 64;
  const int ng = t & 15;
  const int co0 = (t >> 4) * 4;
  const int nl0 = ng * 4;

  float accp[4][3][4] = {};
  float accd[4][3][4] = {};

  for (int chunk = 0; chunk < CIN / 64; ++chunk) {
    const int kb = chunk * 64;
    const float* hbase = h + ((size_t)(b * CIN + kb) * 3) * NP + n0;
    __syncthreads();
#pragma unroll
    for (int i = 0; i < 12; ++i) {     // 192 rows x 64 floats
      int flat = i * 256 + t;
      int row = flat >> 4;
      int c4 = (flat & 15) * 4;
      *(float4*)&hs[row * 64 + c4] = *(const float4*)&hbase[(size_t)row * NP + c4];
    }
    {
      const float* Ws = (PHASE == 1) ? Wd : Wp;
#pragma unroll
      for (int i = 0; i < 16; ++i) {
        int flat = i * 256 + t;
        int co = flat >> 6, k = flat & 63;
        wls[k * 64 + (co ^ ((k & 15) << 2))] = Ws[(cobase + co) * CIN + kb + k];
      }
    }
    __syncthreads();
    if (PHASE == 1) {
#pragma unroll 2
      for (int k = 0; k < 64; ++k) fma_step(wls, hs, k, co0, nl0, accd);
      __syncthreads();
#pragma unroll
      for (int i = 0; i < 16; ++i) {
        int flat = i * 256 + t;
        int co = flat >> 6, k = flat & 63;
        wls[k * 64 + (co ^ ((k & 15) << 2))] = Wp[(cobase + co) * CIN + kb + k];
      }
      __syncthreads();
    }
#pragma unroll 2
    for (int k = 0; k < 64; ++k) fma_step(wls, hs, k, co0, nl0, accp);
  }

  if (PHASE == 0) {
#pragma unroll
    for (int ci = 0; ci < 4; ++ci) {
      float s = 0.f, ss = 0.f;
#pragma unroll
      for (int nj = 0; nj < 4; ++nj) {
        float nsq = accp[ci][0][nj] * accp[ci][0][nj] +
                    accp[ci][1][nj] * accp[ci][1][nj] +
                    accp[ci][2][nj] * accp[ci][2][nj];
        float nm = sqrtf(nsq) + VEPS;
        s += nm; ss += nm * nm;
      }
#pragma unroll
      for (int m = 1; m < 16; m <<= 1) {
        s += __shfl_xor(s, m, 64);
        ss += __shfl_xor(ss, m, 64);
      }
      if (ng == 0) {
        atomicAdd(&stage[cobase + co0 + ci], s);
        atomicAdd(&stage[COUT + cobase + co0 + ci], ss);
      }
    }
  } else if (PHASE == 1) {
#pragma unroll
    for (int ci = 0; ci < 4; ++ci) {
      const int ch = cobase + co0 + ci;
      const float sc = stage[2 * COUT + ch], mn = stage[3 * COUT + ch], be = beta[ch];
#pragma unroll
      for (int nj = 0; nj < 4; ++nj) {
        float px = accp[ci][0][nj], py = accp[ci][1][nj], pz = accp[ci][2][nj];
        float nm = sqrtf(px * px + py * py + pz * pz) + VEPS;
        float fac = (sc * (nm - mn) + be) / nm;
        px *= fac; py *= fac; pz *= fac;
        float dx = accd[ci][0][nj], dy = accd[ci][1][nj], dz = accd[ci][2][nj];
        float dot = px * dx + py * dy + pz * dz;
        if (dot < 0.f) {
          float tt = dot / (dx * dx + dy * dy + dz * dz + VEPS);
          px -= tt * dx; py -= tt * dy; pz -= tt * dz;
        }
        accp[ci][0][nj] = px; accp[ci][1][nj] = py; accp[ci][2][nj] = pz;
      }
#pragma unroll
      for (int v = 0; v < 3; ++v) {
        float4 o;
        o.x = accp[ci][v][0]; o.y = accp[ci][v][1];
        o.z = accp[ci][v][2]; o.w = accp[ci][v][3];
        *(float4*)&out[((size_t)(b * COUT + ch) * 3 + v) * NP + n0 + nl0] = o;
      }
    }
  } else {  // PHASE == 2
    const float invN = 1.f / (float)NP;
#pragma unroll
    for (int ci = 0; ci < 4; ++ci) {
      const int ch = cobase + co0 + ci;
      const float sc = stage[2 * COUT + ch], mn = stage[3 * COUT + ch], be = beta[ch];
      float p0 = 0.f, p1 = 0.f, p2 = 0.f;
#pragma unroll
      for (int nj = 0; nj < 4; ++nj) {
        float px = accp[ci][0][nj], py = accp[ci][1][nj], pz = accp[ci][2][nj];
        float nm = sqrtf(px * px + py * py + pz * pz) + VEPS;
        float fac = (sc * (nm - mn) + be) / nm;
        p0 += px * fac; p1 += py * fac; p2 += pz * fac;
      }
#pragma unroll
      for (int m = 1; m < 16; m <<= 1) {
        p0 += __shfl_xor(p0, m, 64);
        p1 += __shfl_xor(p1, m, 64);
        p2 += __shfl_xor(p2, m, 64);
      }
      if (ng == 0) {
        atomicAdd(&out[(size_t)(b * COUT + ch) * 3 + 0], p0 * invN);
        atomicAdd(&out[(size_t)(b * COUT + ch) * 3 + 1], p1 * invN);
        atomicAdd(&out[(size_t)(b * COUT + ch) * 3 + 2], p2 * invN);
      }
    }
  }
}

extern "C" void kernel_launch(void* const* d_in, const int* in_sizes, int n_in,
                              void* d_out, int out_size, void* d_ws, size_t ws_size,
                              hipStream_t stream) {
  const float* x  = (const float*)d_in[0];
  const float* W1 = (const float*)d_in[1];
  const float* D1 = (const float*)d_in[2];
  const float* g1 = (const float*)d_in[3];
  const float* b1 = (const float*)d_in[4];
  const float* W2 = (const float*)d_in[5];
  const float* D2 = (const float*)d_in[6];
  const float* g2 = (const float*)d_in[7];
  const float* b2 = (const float*)d_in[8];
  const float* W3 = (const float*)d_in[9];
  const float* D3 = (const float*)d_in[10];
  const float* g3 = (const float*)d_in[11];
  const float* b3 = (const float*)d_in[12];
  const float* W4 = (const float*)d_in[13];
  const float* D4 = (const float*)d_in[14];
  const float* g4 = (const float*)d_in[15];
  const float* b4 = (const float*)d_in[16];
  const float* W5 = (const float*)d_in[17];
  const float* g5 = (const float*)d_in[18];
  const float* b5 = (const float*)d_in[19];
  float* outp = (float*)d_out;

  char* ws = (char*)d_ws;
  size_t off = 0;
  int* idxw = (int*)(ws + off); off += 4ull * NB * NP * KNB;
  off = (off + 255) & ~255ull;
  float* stats = (float*)(ws + off); off += 4ull * 20480;
  off = (off + 255) & ~255ull;
  float* hA = (float*)(ws + off); off += 4ull * NB * 64 * 3 * NP;
  off = (off + 255) & ~255ull;
  float* hB = (float*)(ws + off); off += 4ull * NB * 128 * 3 * NP;

  float* st1 = stats;
  float* st2 = stats + 4096;
  float* st3 = stats + 8192;
  float* st4 = stats + 12288;
  float* st5 = stats + 16384;

  zero_kernel<<<80, 256, 0, stream>>>(outp, out_size, stats, 20480);
  knn_kernel<<<NB * 128, 512, 0, stream>>>(x, idxw);

  bn1_stats_kernel<<<256, 256, 0, stream>>>(x, idxw, W1, st1);
  bn_finalize_kernel<<<1, 64, 0, stream>>>(st1, g1, 64, 1.f / (float)(NB * NP * KNB));
  block1_apply_kernel<<<NB * 256, 256, 0, stream>>>(x, idxw, W1, D1, st1, b1, hA);

  vn_gemm_kernel<64, 64, 0><<<dim3(64, 1, NB), 256, 0, stream>>>(hA, W2, nullptr, st2, nullptr, nullptr);
  bn_finalize_kernel<<<1, 64, 0, stream>>>(st2, g2, 64, 1.f / (float)(NB * NP));
  vn_gemm_kernel<64, 64, 1><<<dim3(64, 1, NB), 256, 0, stream>>>(hA, W2, D2, st2, b2, hB);

  vn_gemm_kernel<64, 64, 0><<<dim3(64, 1, NB), 256, 0, stream>>>(hB, W3, nullptr, st3, nullptr, nullptr);
  bn_finalize_kernel<<<1, 64, 0, stream>>>(st3, g3, 64, 1.f / (float)(NB * NP));
  vn_gemm_kernel<64, 64, 1><<<dim3(64, 1, NB), 256, 0, stream>>>(hB, W3, D3, st3, b3, hA);

  vn_gemm_kernel<64, 128, 0><<<dim3(64, 2, NB), 256, 0, stream>>>(hA, W4, nullptr, st4, nullptr, nullptr);
  bn_finalize_kernel<<<1, 128, 0, stream>>>(st4, g4, 128, 1.f / (float)(NB * NP));
  vn_gemm_kernel<64, 128, 1><<<dim3(64, 2, NB), 256, 0, stream>>>(hA, W4, D4, st4, b4, hB);

  vn_gemm_kernel<128, 1024, 0><<<dim3(64, 16, NB), 256, 0, stream>>>(hB, W5, nullptr, st5, nullptr, nullptr);
  bn_finalize_kernel<<<4, 256, 0, stream>>>(st5, g5, 1024, 1.f / (float)(NB * NP));
  vn_gemm_kernel<128, 1024, 2><<<dim3(64, 16, NB), 256, 0, stream>>>(hB, W5, nullptr, st5, b5, outp);
}